// Round 6
// baseline (239.650 us; speedup 1.0000x reference)
//
#include <hip/hip_runtime.h>

typedef float f32x16 __attribute__((ext_vector_type(16)));
typedef __bf16 bf16x8 __attribute__((ext_vector_type(8)));
typedef unsigned int uint2v __attribute__((ext_vector_type(2)));

#define Hh 16
#define Dd 128
#define SEQ 2048
#define HD 2048                      // Hh*Dd
#define ATT_C 0.12751743f            // (1/sqrt(128)) * log2(e)
#define NEGINF (-__builtin_inff())

__device__ __forceinline__ ushort f2bf(float f) {
    uint u = __builtin_bit_cast(uint, f);
    return (ushort)((u + 0x7FFFu + ((u >> 16) & 1u)) >> 16);
}

__device__ __forceinline__ uint4 pack8(float4 a, float4 b) {
    uint4 u;
    u.x = (uint)f2bf(a.x) | ((uint)f2bf(a.y) << 16);
    u.y = (uint)f2bf(a.z) | ((uint)f2bf(a.w) << 16);
    u.z = (uint)f2bf(b.x) | ((uint)f2bf(b.y) << 16);
    u.w = (uint)f2bf(b.z) | ((uint)f2bf(b.w) << 16);
    return u;
}

// single-instruction packed f32->bf16 (RNE), low=a high=b
__device__ __forceinline__ uint cvtpk(float a, float b) {
    uint r;
    asm("v_cvt_pk_bf16_f32 %0, %1, %2" : "=v"(r) : "v"(a), "v"(b));
    return r;
}

__device__ __forceinline__ f32x16 zero16() {
    f32x16 v;
#pragma unroll
    for (int i = 0; i < 16; ++i) v[i] = 0.f;
    return v;
}

__device__ __forceinline__ float hmax16(const f32x16 v) {
    float a0 = fmaxf(v[0], v[1]), a1 = fmaxf(v[2], v[3]);
    float a2 = fmaxf(v[4], v[5]), a3 = fmaxf(v[6], v[7]);
    float a4 = fmaxf(v[8], v[9]), a5 = fmaxf(v[10], v[11]);
    float a6 = fmaxf(v[12], v[13]), a7 = fmaxf(v[14], v[15]);
    float b0 = fmaxf(a0, a1), b1 = fmaxf(a2, a3), b2 = fmaxf(a4, a5), b3 = fmaxf(a6, a7);
    return fmaxf(fmaxf(b0, b1), fmaxf(b2, b3));
}
__device__ __forceinline__ float hsum16(const f32x16 v) {
    float a0 = v[0] + v[1], a1 = v[2] + v[3], a2 = v[4] + v[5], a3 = v[6] + v[7];
    float a4 = v[8] + v[9], a5 = v[10] + v[11], a6 = v[12] + v[13], a7 = v[14] + v[15];
    float b0 = a0 + a1, b1 = a2 + a3, b2 = a4 + a5, b3 = a6 + a7;
    return (b0 + b1) + (b2 + b3);
}

// async global->LDS, 16 B per lane (dest must be tid-linear)
__device__ __forceinline__ void gll16(const void* g, void* l) {
    __builtin_amdgcn_global_load_lds(
        (const __attribute__((address_space(1))) unsigned int*)g,
        (__attribute__((address_space(3))) unsigned int*)l, 16, 0, 0);
}

// PV A-fragment assembly via permlane32_swap (verified R2/R4)
__device__ __forceinline__ bf16x8 mkfrag(uint a01, uint a23, uint a45, uint a67, int hi) {
    uint4 u;
#if __has_builtin(__builtin_amdgcn_permlane32_swap)
    uint2v xz = __builtin_amdgcn_permlane32_swap(a01, a45, false, false);
    uint2v yw = __builtin_amdgcn_permlane32_swap(a23, a67, false, false);
    u.x = xz[0]; u.y = yw[0]; u.z = xz[1]; u.w = yw[1];
    (void)hi;
#else
    uint s01 = __shfl_xor(a01, 32), s23 = __shfl_xor(a23, 32);
    uint s45 = __shfl_xor(a45, 32), s67 = __shfl_xor(a67, 32);
    u.x = hi ? s45 : a01;
    u.y = hi ? s67 : a23;
    u.z = hi ? a45 : s01;
    u.w = hi ? a67 : s23;
#endif
    return __builtin_bit_cast(bf16x8, u);
}

// ---- inverse slot map ----
__global__ void initinv(int* __restrict__ inv, int T) {
    int i = blockIdx.x * 256 + threadIdx.x;
    if (i < T) inv[i] = -1;
}
__global__ void buildinv(const int* __restrict__ slots, int* __restrict__ inv, int T) {
    int t = blockIdx.x * 256 + threadIdx.x;
    if (t < T) { int s = slots[t]; if (s >= 0 && s < T) inv[s] = t; }
}

// ---- fused effective-KV materialization into FRAGMENT-MAJOR 16KB tiles ----
__global__ void fusekv(const float* __restrict__ k, const float* __restrict__ v,
                       const float* __restrict__ kc, const float* __restrict__ vc,
                       const int* __restrict__ inv, ushort* __restrict__ ek,
                       ushort* __restrict__ evt) {
    __shared__ int sv[64];
    __shared__ ushort Ks[64][136];
    __shared__ ushort Lt[128][72];
    const int tid = threadIdx.x;
    const int r0 = blockIdx.x * 64, h = blockIdx.y;
    const int b = r0 >> 11, tok0 = r0 & (SEQ - 1);
    const long tb = ((long)(b * Hh + h) * 32 + (tok0 >> 6)) * 8192;
    if (tid < 64) sv[tid] = inv[r0 + tid];
    __syncthreads();
#pragma unroll
    for (int i = 0; i < 4; ++i) {
        int idx = i * 256 + tid, r = idx >> 4, sg = idx & 15;
        int s = sv[r];
        const float* src = (s >= 0 ? k + (long)s * HD : kc + (long)(r0 + r) * HD) + h * Dd + sg * 8;
        float4 A = *(const float4*)src;
        float4 Bv = *(const float4*)(src + 4);
        *(uint4*)&Ks[r][sg * 8] = pack8(A, Bv);
    }
    const int d = tid & 127, hf2 = tid >> 7;
#pragma unroll
    for (int i = 0; i < 8; ++i) {
        const int t = i * 8 + hf2 * 4;
        ushort wv[4];
#pragma unroll
        for (int jj = 0; jj < 4; ++jj) {
            int s = sv[t + jj];
            const float* sp = (s >= 0 ? v + (long)s * HD : vc + (long)(r0 + t + jj) * HD) + h * Dd + d;
            wv[jj] = f2bf(*sp);
        }
        uint2 u;
        u.x = (uint)wv[0] | ((uint)wv[1] << 16);
        u.y = (uint)wv[2] | ((uint)wv[3] << 16);
        *(uint2*)&Lt[d][t] = u;
    }
    __syncthreads();
#pragma unroll
    for (int i = 0; i < 4; ++i) {
        int c = i * 256 + tid, l = c & 31, j = (c >> 5) & 15, hf = c >> 9;
        *(uint4*)(ek + tb + (long)c * 8) = *(const uint4*)&Ks[hf * 32 + l][j * 8];
    }
#pragma unroll
    for (int i = 0; i < 4; ++i) {
        int c = i * 256 + tid, l = c & 31, ch = (c >> 5) & 7, nt = c >> 8;
        *(uint4*)(evt + tb + (long)c * 8) = *(const uint4*)&Lt[nt * 32 + l][ch * 8];
    }
}

// QK for one 64-key tile into zn0/zn1 via 4 independent MFMA chains.
#define QKB(QF) { \
    f32x16 a0 = zero16(), b0 = zero16(), a1 = zero16(), b1 = zero16(); \
    _Pragma("unroll") \
    for (int kk = 0; kk < 4; ++kk) { \
        a0 = __builtin_amdgcn_mfma_f32_32x32x16_bf16(*(const bf16x8*)&Kb[kk * 512 + koff], QF[kk], a0, 0, 0, 0); \
        a1 = __builtin_amdgcn_mfma_f32_32x32x16_bf16(*(const bf16x8*)&Kb[4096 + kk * 512 + koff], QF[kk], a1, 0, 0, 0); \
        b0 = __builtin_amdgcn_mfma_f32_32x32x16_bf16(*(const bf16x8*)&Kb[(kk + 4) * 512 + koff], QF[kk + 4], b0, 0, 0, 0); \
        b1 = __builtin_amdgcn_mfma_f32_32x32x16_bf16(*(const bf16x8*)&Kb[4096 + (kk + 4) * 512 + koff], QF[kk + 4], b1, 0, 0, 0); \
    } \
    zn0 = a0 + b0; zn1 = a1 + b1; }

// ---- causal flash attention: software-pipelined tiles + counted-vmcnt 4-buf ----
__global__ __launch_bounds__(512, 2) void attn32(const float* __restrict__ q,
                                                 const ushort* __restrict__ ek,
                                                 const ushort* __restrict__ evt,
                                                 float* __restrict__ out) {
    __shared__ ushort KV[4][16384];  // 4 bufs x [K 8192 | V 8192] shorts = 128 KB

    const int tid = threadIdx.x;
    const int w = tid >> 6, lane = tid & 63;
    const int l31 = lane & 31, hi = lane >> 5;
    const int g = blockIdx.x;
    const int bh = g & 63, jp = g >> 6;
    const int b = bh >> 4, h = bh & 15;
    const int n1 = 4 * (jp + 1), ns = 36;
    const long kvbase = (long)bh * 32 * 8192;
    const int koff = hi * 256 + l31 * 8;

    bf16x8 qfA[8], qfB[8];
    auto loadq = [&](int qt_, bf16x8* qf) {
        const int qrow = qt_ * 256 + w * 32 + l31;
        const float* qp = q + ((long)(b * SEQ + qrow) * Hh + h) * Dd + hi * 8;
#pragma unroll
        for (int kk = 0; kk < 8; ++kk) {
            float4 A = *(const float4*)(qp + kk * 16);
            float4 Bv = *(const float4*)(qp + kk * 16 + 4);
            A.x *= ATT_C; A.y *= ATT_C; A.z *= ATT_C; A.w *= ATT_C;
            Bv.x *= ATT_C; Bv.y *= ATT_C; Bv.z *= ATT_C; Bv.w *= ATT_C;
            union { uint4 u; bf16x8 v; } cv;
            cv.u = pack8(A, Bv);
            qf[kk] = cv.v;
        }
    };
    auto stage = [&](int nb, int t) {
        const ushort* kg = ek + kvbase + (long)t * 8192 + tid * 8;
        const ushort* vg = evt + kvbase + (long)t * 8192 + tid * 8;
        ushort* kl = &KV[nb][tid * 8];
        ushort* vl = &KV[nb][8192 + tid * 8];
#pragma unroll
        for (int i = 0; i < 2; ++i) {
            gll16(kg + i * 4096, kl + i * 4096);
            gll16(vg + i * 4096, vl + i * 4096);
        }
    };

    f32x16 o[4];
#pragma unroll
    for (int nt = 0; nt < 4; ++nt) o[nt] = zero16();
    float m = NEGINF, lsum = 0.f;

    // mask + tile-max for a freshly computed z pair
    auto masknext = [&](int kv0n, int qtbn, f32x16& zn0, f32x16& zn1) -> float {
        float mm = NEGINF;
        if (kv0n + 63 > qtbn) {
            const int qpn = qtbn + l31;
#pragma unroll
            for (int r = 0; r < 16; ++r) {
                const int kr = kv0n + ((r & 3) + 8 * (r >> 2) + 4 * hi);
                float a0 = (kr <= qpn) ? zn0[r] : NEGINF;
                float a1 = (kr + 32 <= qpn) ? zn1[r] : NEGINF;
                zn0[r] = a0; zn1[r] = a1;
                mm = fmaxf(mm, fmaxf(a0, a1));
            }
        } else {
            mm = fmaxf(hmax16(zn0), hmax16(zn1));
        }
        return fmaxf(mm, __shfl_xor(mm, 32));
    };

    // ---- prologue ----
    loadq(jp, qfA);
    loadq(7 - jp, qfB);
    stage(0, 0); stage(1, 1); stage(2, 2);
    asm volatile("s_waitcnt vmcnt(8)" ::: "memory");   // tile0 loaded (per-wave)
    __builtin_amdgcn_sched_barrier(0);
    __builtin_amdgcn_s_barrier();                      // tile0 visible block-wide

    f32x16 zA0, zA1, zB0, zB1;
    float mA = NEGINF, mB = NEGINF;
    {
        const ushort* Kb = &KV[0][0];
        f32x16& zn0 = zA0; f32x16& zn1 = zA1;
        QKB(qfA);
        mA = masknext(0, jp * 256 + w * 32, zA0, zA1);
    }
    asm volatile("s_waitcnt vmcnt(4)" ::: "memory");   // tile1 loaded
    __builtin_amdgcn_sched_barrier(0);
    __builtin_amdgcn_s_barrier();

    auto body = [&](int s, f32x16& zc0, f32x16& zc1, float& mtc,
                    f32x16& zn0_, f32x16& zn1_, float& mtn) {
        const int kv0c = ((s < n1) ? s : s - n1) * 64;
        const int qtbc = ((s < n1) ? jp : 7 - jp) * 256 + w * 32;
        const bool liveC = (kv0c <= qtbc + 31);
        const int sp1 = s + 1;
        const bool haveN = (sp1 < ns);
        const int kv0n = haveN ? (((sp1 < n1) ? sp1 : sp1 - n1) * 64) : 0;
        const int qtbn = ((sp1 < n1) ? jp : 7 - jp) * 256 + w * 32;
        const bool liveN = haveN && (kv0n <= qtbn + 31);

        // 1) stage 3 tiles ahead
        if (s + 3 < ns) stage((s + 3) & 3, (s + 3 < n1) ? s + 3 : s + 3 - n1);

        // 2) QK of next tile (MFMA) — overlaps the VALU softmax below
        if (liveN) {
            const ushort* Kb = &KV[sp1 & 3][0];
            f32x16& zn0 = zn0_; f32x16& zn1 = zn1_;
            __builtin_amdgcn_s_setprio(1);
            if (sp1 < n1) { QKB(qfA) } else { QKB(qfB) }
            __builtin_amdgcn_s_setprio(0);
        }

        // 3) softmax-finish of current tile (VALU)
        if (liveC) {
            if (!__all(mtc <= m + 8.f)) {
                const float mn = fmaxf(m, mtc);
                const float al = exp2f(m - mn);
                m = mn;
                lsum *= al;
#pragma unroll
                for (int r = 0; r < 16; ++r) {
                    const float alr = __shfl(al, (r & 3) + 8 * (r >> 2) + 4 * hi);
                    o[0][r] *= alr; o[1][r] *= alr; o[2][r] *= alr; o[3][r] *= alr;
                }
            }
#pragma unroll
            for (int r = 0; r < 16; ++r) {
                zc0[r] = __builtin_amdgcn_exp2f(zc0[r] - m);
                zc1[r] = __builtin_amdgcn_exp2f(zc1[r] - m);
            }
            lsum += hsum16(zc0) + hsum16(zc1);
            bf16x8 pa0 = mkfrag(cvtpk(zc0[0], zc0[1]), cvtpk(zc0[2], zc0[3]),
                                cvtpk(zc0[4], zc0[5]), cvtpk(zc0[6], zc0[7]), hi);
            bf16x8 pa1 = mkfrag(cvtpk(zc0[8], zc0[9]), cvtpk(zc0[10], zc0[11]),
                                cvtpk(zc0[12], zc0[13]), cvtpk(zc0[14], zc0[15]), hi);
            bf16x8 pa2 = mkfrag(cvtpk(zc1[0], zc1[1]), cvtpk(zc1[2], zc1[3]),
                                cvtpk(zc1[4], zc1[5]), cvtpk(zc1[6], zc1[7]), hi);
            bf16x8 pa3 = mkfrag(cvtpk(zc1[8], zc1[9]), cvtpk(zc1[10], zc1[11]),
                                cvtpk(zc1[12], zc1[13]), cvtpk(zc1[14], zc1[15]), hi);
            // 4) PV of current tile (MFMA) — overlaps mask of next tile below
            const ushort* Vb = &KV[s & 3][8192];
            __builtin_amdgcn_s_setprio(1);
#pragma unroll
            for (int nt = 0; nt < 4; ++nt) {
                const int vb = nt * 2048 + koff;
                o[nt] = __builtin_amdgcn_mfma_f32_32x32x16_bf16(pa0, *(const bf16x8*)&Vb[vb], o[nt], 0, 0, 0);
                o[nt] = __builtin_amdgcn_mfma_f32_32x32x16_bf16(pa1, *(const bf16x8*)&Vb[vb + 512], o[nt], 0, 0, 0);
                o[nt] = __builtin_amdgcn_mfma_f32_32x32x16_bf16(pa2, *(const bf16x8*)&Vb[vb + 1024], o[nt], 0, 0, 0);
                o[nt] = __builtin_amdgcn_mfma_f32_32x32x16_bf16(pa3, *(const bf16x8*)&Vb[vb + 1536], o[nt], 0, 0, 0);
            }
            __builtin_amdgcn_s_setprio(0);
        }

        // 5) mask + max of next tile (VALU)
        if (liveN) mtn = masknext(kv0n, qtbn, zn0_, zn1_);

        // 6) per-qtile epilogue
        if (s == n1 - 1 || s == ns - 1) {
            const float lt = lsum + __shfl_xor(lsum, 32);
            const float inv_ = 1.f / lt;
#pragma unroll
            for (int r = 0; r < 16; ++r) {
                const int qr = (r & 3) + 8 * (r >> 2) + 4 * hi;
                const float ivr = __shfl(inv_, qr);
                float* op = out + ((long)(b * SEQ + qtbc + qr) * Hh + h) * Dd + l31;
                op[0] = o[0][r] * ivr;
                op[32] = o[1][r] * ivr;
                op[64] = o[2][r] * ivr;
                op[96] = o[3][r] * ivr;
            }
#pragma unroll
            for (int nt = 0; nt < 4; ++nt) o[nt] = zero16();
            m = NEGINF; lsum = 0.f;
        }

        // 7) counted wait: keep newest stage (4 loads) in flight across barrier
        if (s + 2 < ns) { asm volatile("s_waitcnt vmcnt(4)" ::: "memory"); }
        else            { asm volatile("s_waitcnt vmcnt(0)" ::: "memory"); }
        __builtin_amdgcn_sched_barrier(0);
        __builtin_amdgcn_s_barrier();
    };

    for (int s = 0; s < ns; s += 2) {
        body(s,     zA0, zA1, mA, zB0, zB1, mB);
        body(s + 1, zB0, zB1, mB, zA0, zA1, mA);
    }
}

extern "C" void kernel_launch(void* const* d_in, const int* in_sizes, int n_in,
                              void* d_out, int out_size, void* d_ws, size_t ws_size,
                              hipStream_t stream) {
    const float* q = (const float*)d_in[0];
    const float* k = (const float*)d_in[1];
    const float* v = (const float*)d_in[2];
    const float* k_cache = (const float*)d_in[3];
    const float* v_cache = (const float*)d_in[4];
    const int* slot_mapping = (const int*)d_in[5];
    float* out = (float*)d_out;

    const int T = in_sizes[0] / HD;  // 8192
    (void)n_in; (void)out_size; (void)ws_size;

    ushort* ek = (ushort*)d_ws;                 // fragment-major K tiles (32 MB)
    ushort* evt = ek + (size_t)T * HD;          // fragment-major V tiles (32 MB)
    int* inv = (int*)(evt + (size_t)T * HD);    // [T] inverse slot map

    initinv<<<T / 256, 256, 0, stream>>>(inv, T);
    buildinv<<<T / 256, 256, 0, stream>>>(slot_mapping, inv, T);
    fusekv<<<dim3(T / 64, Hh), 256, 0, stream>>>(k, v, k_cache, v_cache, inv, ek, evt);
    attn32<<<dim3(256), 512, 0, stream>>>(q, ek, evt, out);
}

// Round 7
// 237.528 us; speedup vs baseline: 1.0089x; 1.0089x over previous
//
#include <hip/hip_runtime.h>

typedef float f32x16 __attribute__((ext_vector_type(16)));
typedef __bf16 bf16x8 __attribute__((ext_vector_type(8)));
typedef unsigned int uint2v __attribute__((ext_vector_type(2)));

#define Hh 16
#define Dd 128
#define SEQ 2048
#define HD 2048                      // Hh*Dd
#define ATT_C 0.12751743f            // (1/sqrt(128)) * log2(e)
#define NEGINF (-__builtin_inff())

__device__ __forceinline__ ushort f2bf(float f) {
    uint u = __builtin_bit_cast(uint, f);
    return (ushort)((u + 0x7FFFu + ((u >> 16) & 1u)) >> 16);
}

__device__ __forceinline__ uint4 pack8(float4 a, float4 b) {
    uint4 u;
    u.x = (uint)f2bf(a.x) | ((uint)f2bf(a.y) << 16);
    u.y = (uint)f2bf(a.z) | ((uint)f2bf(a.w) << 16);
    u.z = (uint)f2bf(b.x) | ((uint)f2bf(b.y) << 16);
    u.w = (uint)f2bf(b.z) | ((uint)f2bf(b.w) << 16);
    return u;
}

// single-instruction packed f32->bf16 (RNE), low=a high=b
__device__ __forceinline__ uint cvtpk(float a, float b) {
    uint r;
    asm("v_cvt_pk_bf16_f32 %0, %1, %2" : "=v"(r) : "v"(a), "v"(b));
    return r;
}

__device__ __forceinline__ f32x16 zero16() {
    f32x16 v;
#pragma unroll
    for (int i = 0; i < 16; ++i) v[i] = 0.f;
    return v;
}

__device__ __forceinline__ float hmax16(const f32x16 v) {
    float a0 = fmaxf(v[0], v[1]), a1 = fmaxf(v[2], v[3]);
    float a2 = fmaxf(v[4], v[5]), a3 = fmaxf(v[6], v[7]);
    float a4 = fmaxf(v[8], v[9]), a5 = fmaxf(v[10], v[11]);
    float a6 = fmaxf(v[12], v[13]), a7 = fmaxf(v[14], v[15]);
    float b0 = fmaxf(a0, a1), b1 = fmaxf(a2, a3), b2 = fmaxf(a4, a5), b3 = fmaxf(a6, a7);
    return fmaxf(fmaxf(b0, b1), fmaxf(b2, b3));
}
__device__ __forceinline__ float hsum16(const f32x16 v) {
    float a0 = v[0] + v[1], a1 = v[2] + v[3], a2 = v[4] + v[5], a3 = v[6] + v[7];
    float a4 = v[8] + v[9], a5 = v[10] + v[11], a6 = v[12] + v[13], a7 = v[14] + v[15];
    float b0 = a0 + a1, b1 = a2 + a3, b2 = a4 + a5, b3 = a6 + a7;
    return (b0 + b1) + (b2 + b3);
}

// async global->LDS, 16 B per lane (dest must be tid-linear)
__device__ __forceinline__ void gll16(const void* g, void* l) {
    __builtin_amdgcn_global_load_lds(
        (const __attribute__((address_space(1))) unsigned int*)g,
        (__attribute__((address_space(3))) unsigned int*)l, 16, 0, 0);
}

// PV A-fragment assembly via permlane32_swap (verified R2/R4)
__device__ __forceinline__ bf16x8 mkfrag(uint a01, uint a23, uint a45, uint a67, int hi) {
    uint4 u;
#if __has_builtin(__builtin_amdgcn_permlane32_swap)
    uint2v xz = __builtin_amdgcn_permlane32_swap(a01, a45, false, false);
    uint2v yw = __builtin_amdgcn_permlane32_swap(a23, a67, false, false);
    u.x = xz[0]; u.y = yw[0]; u.z = xz[1]; u.w = yw[1];
    (void)hi;
#else
    uint s01 = __shfl_xor(a01, 32), s23 = __shfl_xor(a23, 32);
    uint s45 = __shfl_xor(a45, 32), s67 = __shfl_xor(a67, 32);
    u.x = hi ? s45 : a01;
    u.y = hi ? s67 : a23;
    u.z = hi ? a45 : s01;
    u.w = hi ? a67 : s23;
#endif
    return __builtin_bit_cast(bf16x8, u);
}

// ---- inverse slot map ----
__global__ void initinv(int* __restrict__ inv, int T) {
    int i = blockIdx.x * 256 + threadIdx.x;
    if (i < T) inv[i] = -1;
}
__global__ void buildinv(const int* __restrict__ slots, int* __restrict__ inv, int T) {
    int t = blockIdx.x * 256 + threadIdx.x;
    if (t < T) { int s = slots[t]; if (s >= 0 && s < T) inv[s] = t; }
}

// ---- fused effective-KV materialization into FRAGMENT-MAJOR 16KB tiles ----
__global__ void fusekv(const float* __restrict__ k, const float* __restrict__ v,
                       const float* __restrict__ kc, const float* __restrict__ vc,
                       const int* __restrict__ inv, ushort* __restrict__ ek,
                       ushort* __restrict__ evt) {
    __shared__ int sv[64];
    __shared__ ushort Ks[64][136];
    __shared__ ushort Lt[128][72];
    const int tid = threadIdx.x;
    const int r0 = blockIdx.x * 64, h = blockIdx.y;
    const int b = r0 >> 11, tok0 = r0 & (SEQ - 1);
    const long tb = ((long)(b * Hh + h) * 32 + (tok0 >> 6)) * 8192;
    if (tid < 64) sv[tid] = inv[r0 + tid];
    __syncthreads();
#pragma unroll
    for (int i = 0; i < 4; ++i) {
        int idx = i * 256 + tid, r = idx >> 4, sg = idx & 15;
        int s = sv[r];
        const float* src = (s >= 0 ? k + (long)s * HD : kc + (long)(r0 + r) * HD) + h * Dd + sg * 8;
        float4 A = *(const float4*)src;
        float4 Bv = *(const float4*)(src + 4);
        *(uint4*)&Ks[r][sg * 8] = pack8(A, Bv);
    }
    const int d = tid & 127, hf2 = tid >> 7;
#pragma unroll
    for (int i = 0; i < 8; ++i) {
        const int t = i * 8 + hf2 * 4;
        ushort wv[4];
#pragma unroll
        for (int jj = 0; jj < 4; ++jj) {
            int s = sv[t + jj];
            const float* sp = (s >= 0 ? v + (long)s * HD : vc + (long)(r0 + t + jj) * HD) + h * Dd + d;
            wv[jj] = f2bf(*sp);
        }
        uint2 u;
        u.x = (uint)wv[0] | ((uint)wv[1] << 16);
        u.y = (uint)wv[2] | ((uint)wv[3] << 16);
        *(uint2*)&Lt[d][t] = u;
    }
    __syncthreads();
#pragma unroll
    for (int i = 0; i < 4; ++i) {
        int c = i * 256 + tid, l = c & 31, j = (c >> 5) & 15, hf = c >> 9;
        *(uint4*)(ek + tb + (long)c * 8) = *(const uint4*)&Ks[hf * 32 + l][j * 8];
    }
#pragma unroll
    for (int i = 0; i < 4; ++i) {
        int c = i * 256 + tid, l = c & 31, ch = (c >> 5) & 7, nt = c >> 8;
        *(uint4*)(evt + tb + (long)c * 8) = *(const uint4*)&Lt[nt * 32 + l][ch * 8];
    }
}

// QK for one 64-key tile into zn0/zn1 via 4 independent MFMA chains.
#define QKB(QF) { \
    f32x16 a0 = zero16(), b0 = zero16(), a1 = zero16(), b1 = zero16(); \
    _Pragma("unroll") \
    for (int kk = 0; kk < 4; ++kk) { \
        a0 = __builtin_amdgcn_mfma_f32_32x32x16_bf16(*(const bf16x8*)&Kb[kk * 512 + koff], QF[kk], a0, 0, 0, 0); \
        a1 = __builtin_amdgcn_mfma_f32_32x32x16_bf16(*(const bf16x8*)&Kb[4096 + kk * 512 + koff], QF[kk], a1, 0, 0, 0); \
        b0 = __builtin_amdgcn_mfma_f32_32x32x16_bf16(*(const bf16x8*)&Kb[(kk + 4) * 512 + koff], QF[kk + 4], b0, 0, 0, 0); \
        b1 = __builtin_amdgcn_mfma_f32_32x32x16_bf16(*(const bf16x8*)&Kb[4096 + (kk + 4) * 512 + koff], QF[kk + 4], b1, 0, 0, 0); \
    } \
    zn0 = a0 + b0; zn1 = a1 + b1; }

// ---- causal flash attention: software-pipelined tiles, 4-buf counted vmcnt ----
// 1 block/CU (128 KB LDS), 8 waves, full 256-VGPR budget (HK/AITER config).
__global__ __launch_bounds__(512, 1) void attn32(const float* __restrict__ q,
                                                 const ushort* __restrict__ ek,
                                                 const ushort* __restrict__ evt,
                                                 float* __restrict__ out) {
    __shared__ ushort KV[4][16384];  // 4 bufs x [K 8192 | V 8192] shorts = 128 KB

    const int tid = threadIdx.x;
    const int w = tid >> 6, lane = tid & 63;
    const int l31 = lane & 31, hi = lane >> 5;
    const int g = blockIdx.x;
    const int bh = g & 63, jp = g >> 6;
    const int b = bh >> 4, h = bh & 15;
    const int n1 = 4 * (jp + 1), ns = 36;
    const long kvbase = (long)bh * 32 * 8192;
    const int koff = hi * 256 + l31 * 8;

    bf16x8 qfA[8], qfB[8];
    auto loadq = [&](int qt_, bf16x8* qf) {
        const int qrow = qt_ * 256 + w * 32 + l31;
        const float* qp = q + ((long)(b * SEQ + qrow) * Hh + h) * Dd + hi * 8;
#pragma unroll
        for (int kk = 0; kk < 8; ++kk) {
            float4 A = *(const float4*)(qp + kk * 16);
            float4 Bv = *(const float4*)(qp + kk * 16 + 4);
            A.x *= ATT_C; A.y *= ATT_C; A.z *= ATT_C; A.w *= ATT_C;
            Bv.x *= ATT_C; Bv.y *= ATT_C; Bv.z *= ATT_C; Bv.w *= ATT_C;
            union { uint4 u; bf16x8 v; } cv;
            cv.u = pack8(A, Bv);
            qf[kk] = cv.v;
        }
    };
    auto stage = [&](int nb, int t) {
        const ushort* kg = ek + kvbase + (long)t * 8192 + tid * 8;
        const ushort* vg = evt + kvbase + (long)t * 8192 + tid * 8;
        ushort* kl = &KV[nb][tid * 8];
        ushort* vl = &KV[nb][8192 + tid * 8];
#pragma unroll
        for (int i = 0; i < 2; ++i) {
            gll16(kg + i * 4096, kl + i * 4096);
            gll16(vg + i * 4096, vl + i * 4096);
        }
    };

    f32x16 o[4];
#pragma unroll
    for (int nt = 0; nt < 4; ++nt) o[nt] = zero16();
    float m = NEGINF, lsum = 0.f;

    // mask + tile-max for a freshly computed z pair
    auto masknext = [&](int kv0n, int qtbn, f32x16& zn0, f32x16& zn1) -> float {
        float mm = NEGINF;
        if (kv0n + 63 > qtbn) {
            const int qpn = qtbn + l31;
#pragma unroll
            for (int r = 0; r < 16; ++r) {
                const int kr = kv0n + ((r & 3) + 8 * (r >> 2) + 4 * hi);
                float a0 = (kr <= qpn) ? zn0[r] : NEGINF;
                float a1 = (kr + 32 <= qpn) ? zn1[r] : NEGINF;
                zn0[r] = a0; zn1[r] = a1;
                mm = fmaxf(mm, fmaxf(a0, a1));
            }
        } else {
            mm = fmaxf(hmax16(zn0), hmax16(zn1));
        }
        return fmaxf(mm, __shfl_xor(mm, 32));
    };

    // ---- prologue ----
    loadq(jp, qfA);
    loadq(7 - jp, qfB);
    stage(0, 0); stage(1, 1); stage(2, 2);
    asm volatile("s_waitcnt vmcnt(8)" ::: "memory");   // tile0 loaded (per-wave)
    __builtin_amdgcn_sched_barrier(0);
    __builtin_amdgcn_s_barrier();                      // tile0 visible block-wide

    f32x16 zA0, zA1, zB0, zB1;
    float mA = NEGINF, mB = NEGINF;
    {
        const ushort* Kb = &KV[0][0];
        f32x16& zn0 = zA0; f32x16& zn1 = zA1;
        QKB(qfA);
        mA = masknext(0, jp * 256 + w * 32, zA0, zA1);
    }
    asm volatile("s_waitcnt vmcnt(4)" ::: "memory");   // tile1 loaded
    __builtin_amdgcn_sched_barrier(0);
    __builtin_amdgcn_s_barrier();

    auto body = [&](int s, f32x16& zc0, f32x16& zc1, float& mtc,
                    f32x16& zn0_, f32x16& zn1_, float& mtn) {
        const int kv0c = ((s < n1) ? s : s - n1) * 64;
        const int qtbc = ((s < n1) ? jp : 7 - jp) * 256 + w * 32;
        const bool liveC = (kv0c <= qtbc + 31);
        const int sp1 = s + 1;
        const bool haveN = (sp1 < ns);
        const int kv0n = haveN ? (((sp1 < n1) ? sp1 : sp1 - n1) * 64) : 0;
        const int qtbn = ((sp1 < n1) ? jp : 7 - jp) * 256 + w * 32;
        const bool liveN = haveN && (kv0n <= qtbn + 31);

        // 1) stage 3 tiles ahead
        if (s + 3 < ns) stage((s + 3) & 3, (s + 3 < n1) ? s + 3 : s + 3 - n1);

        // 2) QK of next tile (MFMA) — overlaps the VALU softmax below
        if (liveN) {
            const ushort* Kb = &KV[sp1 & 3][0];
            f32x16& zn0 = zn0_; f32x16& zn1 = zn1_;
            __builtin_amdgcn_s_setprio(1);
            if (sp1 < n1) { QKB(qfA) } else { QKB(qfB) }
            __builtin_amdgcn_s_setprio(0);
        }

        // 3) softmax-finish of current tile (VALU)
        if (liveC) {
            if (!__all(mtc <= m + 8.f)) {
                const float mn = fmaxf(m, mtc);
                const float al = exp2f(m - mn);
                m = mn;
                lsum *= al;
#pragma unroll
                for (int r = 0; r < 16; ++r) {
                    const float alr = __shfl(al, (r & 3) + 8 * (r >> 2) + 4 * hi);
                    o[0][r] *= alr; o[1][r] *= alr; o[2][r] *= alr; o[3][r] *= alr;
                }
            }
#pragma unroll
            for (int r = 0; r < 16; ++r) {
                zc0[r] = __builtin_amdgcn_exp2f(zc0[r] - m);
                zc1[r] = __builtin_amdgcn_exp2f(zc1[r] - m);
            }
            lsum += hsum16(zc0) + hsum16(zc1);
            bf16x8 pa0 = mkfrag(cvtpk(zc0[0], zc0[1]), cvtpk(zc0[2], zc0[3]),
                                cvtpk(zc0[4], zc0[5]), cvtpk(zc0[6], zc0[7]), hi);
            bf16x8 pa1 = mkfrag(cvtpk(zc0[8], zc0[9]), cvtpk(zc0[10], zc0[11]),
                                cvtpk(zc0[12], zc0[13]), cvtpk(zc0[14], zc0[15]), hi);
            bf16x8 pa2 = mkfrag(cvtpk(zc1[0], zc1[1]), cvtpk(zc1[2], zc1[3]),
                                cvtpk(zc1[4], zc1[5]), cvtpk(zc1[6], zc1[7]), hi);
            bf16x8 pa3 = mkfrag(cvtpk(zc1[8], zc1[9]), cvtpk(zc1[10], zc1[11]),
                                cvtpk(zc1[12], zc1[13]), cvtpk(zc1[14], zc1[15]), hi);
            // 4) PV of current tile (MFMA) — overlaps mask of next tile below
            const ushort* Vb = &KV[s & 3][8192];
            __builtin_amdgcn_s_setprio(1);
#pragma unroll
            for (int nt = 0; nt < 4; ++nt) {
                const int vb = nt * 2048 + koff;
                o[nt] = __builtin_amdgcn_mfma_f32_32x32x16_bf16(pa0, *(const bf16x8*)&Vb[vb], o[nt], 0, 0, 0);
                o[nt] = __builtin_amdgcn_mfma_f32_32x32x16_bf16(pa1, *(const bf16x8*)&Vb[vb + 512], o[nt], 0, 0, 0);
                o[nt] = __builtin_amdgcn_mfma_f32_32x32x16_bf16(pa2, *(const bf16x8*)&Vb[vb + 1024], o[nt], 0, 0, 0);
                o[nt] = __builtin_amdgcn_mfma_f32_32x32x16_bf16(pa3, *(const bf16x8*)&Vb[vb + 1536], o[nt], 0, 0, 0);
            }
            __builtin_amdgcn_s_setprio(0);
        }

        // 5) mask + max of next tile (VALU)
        if (liveN) mtn = masknext(kv0n, qtbn, zn0_, zn1_);

        // 6) per-qtile epilogue
        if (s == n1 - 1 || s == ns - 1) {
            const float lt = lsum + __shfl_xor(lsum, 32);
            const float inv_ = 1.f / lt;
#pragma unroll
            for (int r = 0; r < 16; ++r) {
                const int qr = (r & 3) + 8 * (r >> 2) + 4 * hi;
                const float ivr = __shfl(inv_, qr);
                float* op = out + ((long)(b * SEQ + qtbc + qr) * Hh + h) * Dd + l31;
                op[0] = o[0][r] * ivr;
                op[32] = o[1][r] * ivr;
                op[64] = o[2][r] * ivr;
                op[96] = o[3][r] * ivr;
            }
#pragma unroll
            for (int nt = 0; nt < 4; ++nt) o[nt] = zero16();
            m = NEGINF; lsum = 0.f;
        }

        // 7) counted wait: keep newest stage (4 loads) in flight across barrier
        if (s + 2 < ns) { asm volatile("s_waitcnt vmcnt(4)" ::: "memory"); }
        else            { asm volatile("s_waitcnt vmcnt(0)" ::: "memory"); }
        __builtin_amdgcn_sched_barrier(0);
        __builtin_amdgcn_s_barrier();
    };

    for (int s = 0; s < ns; s += 2) {
        body(s,     zA0, zA1, mA, zB0, zB1, mB);
        body(s + 1, zB0, zB1, mB, zA0, zA1, mA);
    }
}

extern "C" void kernel_launch(void* const* d_in, const int* in_sizes, int n_in,
                              void* d_out, int out_size, void* d_ws, size_t ws_size,
                              hipStream_t stream) {
    const float* q = (const float*)d_in[0];
    const float* k = (const float*)d_in[1];
    const float* v = (const float*)d_in[2];
    const float* k_cache = (const float*)d_in[3];
    const float* v_cache = (const float*)d_in[4];
    const int* slot_mapping = (const int*)d_in[5];
    float* out = (float*)d_out;

    const int T = in_sizes[0] / HD;  // 8192
    (void)n_in; (void)out_size; (void)ws_size;

    ushort* ek = (ushort*)d_ws;                 // fragment-major K tiles (32 MB)
    ushort* evt = ek + (size_t)T * HD;          // fragment-major V tiles (32 MB)
    int* inv = (int*)(evt + (size_t)T * HD);    // [T] inverse slot map

    initinv<<<T / 256, 256, 0, stream>>>(inv, T);
    buildinv<<<T / 256, 256, 0, stream>>>(slot_mapping, inv, T);
    fusekv<<<dim3(T / 64, Hh), 256, 0, stream>>>(k, v, k_cache, v_cache, inv, ek, evt);
    attn32<<<dim3(256), 512, 0, stream>>>(q, ek, evt, out);
}

// Round 8
// 224.130 us; speedup vs baseline: 1.0692x; 1.0598x over previous
//
#include <hip/hip_runtime.h>

typedef float f32x16 __attribute__((ext_vector_type(16)));
typedef __bf16 bf16x8 __attribute__((ext_vector_type(8)));
typedef unsigned int uint2v __attribute__((ext_vector_type(2)));

#define Hh 16
#define Dd 128
#define SEQ 2048
#define HD 2048                      // Hh*Dd
#define ATT_C 0.12751743f            // (1/sqrt(128)) * log2(e)
#define NEGINF (-__builtin_inff())

__device__ __forceinline__ ushort f2bf(float f) {
    uint u = __builtin_bit_cast(uint, f);
    return (ushort)((u + 0x7FFFu + ((u >> 16) & 1u)) >> 16);
}

__device__ __forceinline__ uint4 pack8(float4 a, float4 b) {
    uint4 u;
    u.x = (uint)f2bf(a.x) | ((uint)f2bf(a.y) << 16);
    u.y = (uint)f2bf(a.z) | ((uint)f2bf(a.w) << 16);
    u.z = (uint)f2bf(b.x) | ((uint)f2bf(b.y) << 16);
    u.w = (uint)f2bf(b.z) | ((uint)f2bf(b.w) << 16);
    return u;
}

// single-instruction packed f32->bf16 (RNE), low=a high=b
__device__ __forceinline__ uint cvtpk(float a, float b) {
    uint r;
    asm("v_cvt_pk_bf16_f32 %0, %1, %2" : "=v"(r) : "v"(a), "v"(b));
    return r;
}

__device__ __forceinline__ f32x16 zero16() {
    f32x16 v;
#pragma unroll
    for (int i = 0; i < 16; ++i) v[i] = 0.f;
    return v;
}

__device__ __forceinline__ float hmax16(const f32x16 v) {
    float a0 = fmaxf(v[0], v[1]), a1 = fmaxf(v[2], v[3]);
    float a2 = fmaxf(v[4], v[5]), a3 = fmaxf(v[6], v[7]);
    float a4 = fmaxf(v[8], v[9]), a5 = fmaxf(v[10], v[11]);
    float a6 = fmaxf(v[12], v[13]), a7 = fmaxf(v[14], v[15]);
    float b0 = fmaxf(a0, a1), b1 = fmaxf(a2, a3), b2 = fmaxf(a4, a5), b3 = fmaxf(a6, a7);
    return fmaxf(fmaxf(b0, b1), fmaxf(b2, b3));
}
__device__ __forceinline__ float hsum16(const f32x16 v) {
    float a0 = v[0] + v[1], a1 = v[2] + v[3], a2 = v[4] + v[5], a3 = v[6] + v[7];
    float a4 = v[8] + v[9], a5 = v[10] + v[11], a6 = v[12] + v[13], a7 = v[14] + v[15];
    float b0 = a0 + a1, b1 = a2 + a3, b2 = a4 + a5, b3 = a6 + a7;
    return (b0 + b1) + (b2 + b3);
}

// async global->LDS, 16 B per lane (dest must be tid-linear)
__device__ __forceinline__ void gll16(const void* g, void* l) {
    __builtin_amdgcn_global_load_lds(
        (const __attribute__((address_space(1))) unsigned int*)g,
        (__attribute__((address_space(3))) unsigned int*)l, 16, 0, 0);
}

// PV A-fragment assembly via permlane32_swap (verified R2/R4)
__device__ __forceinline__ bf16x8 mkfrag(uint a01, uint a23, uint a45, uint a67, int hi) {
    uint4 u;
#if __has_builtin(__builtin_amdgcn_permlane32_swap)
    uint2v xz = __builtin_amdgcn_permlane32_swap(a01, a45, false, false);
    uint2v yw = __builtin_amdgcn_permlane32_swap(a23, a67, false, false);
    u.x = xz[0]; u.y = yw[0]; u.z = xz[1]; u.w = yw[1];
    (void)hi;
#else
    uint s01 = __shfl_xor(a01, 32), s23 = __shfl_xor(a23, 32);
    uint s45 = __shfl_xor(a45, 32), s67 = __shfl_xor(a67, 32);
    u.x = hi ? s45 : a01;
    u.y = hi ? s67 : a23;
    u.z = hi ? a45 : s01;
    u.w = hi ? a67 : s23;
#endif
    return __builtin_bit_cast(bf16x8, u);
}

// ---- inverse slot map ----
__global__ void initinv(int* __restrict__ inv, int T) {
    int i = blockIdx.x * 256 + threadIdx.x;
    if (i < T) inv[i] = -1;
}
__global__ void buildinv(const int* __restrict__ slots, int* __restrict__ inv, int T) {
    int t = blockIdx.x * 256 + threadIdx.x;
    if (t < T) { int s = slots[t]; if (s >= 0 && s < T) inv[s] = t; }
}

// ---- fused effective-KV materialization into FRAGMENT-MAJOR 16KB tiles ----
__global__ void fusekv(const float* __restrict__ k, const float* __restrict__ v,
                       const float* __restrict__ kc, const float* __restrict__ vc,
                       const int* __restrict__ inv, ushort* __restrict__ ek,
                       ushort* __restrict__ evt) {
    __shared__ int sv[64];
    __shared__ ushort Ks[64][136];
    __shared__ ushort Lt[128][72];
    const int tid = threadIdx.x;
    const int r0 = blockIdx.x * 64, h = blockIdx.y;
    const int b = r0 >> 11, tok0 = r0 & (SEQ - 1);
    const long tb = ((long)(b * Hh + h) * 32 + (tok0 >> 6)) * 8192;
    if (tid < 64) sv[tid] = inv[r0 + tid];
    __syncthreads();
#pragma unroll
    for (int i = 0; i < 4; ++i) {
        int idx = i * 256 + tid, r = idx >> 4, sg = idx & 15;
        int s = sv[r];
        const float* src = (s >= 0 ? k + (long)s * HD : kc + (long)(r0 + r) * HD) + h * Dd + sg * 8;
        float4 A = *(const float4*)src;
        float4 Bv = *(const float4*)(src + 4);
        *(uint4*)&Ks[r][sg * 8] = pack8(A, Bv);
    }
    const int d = tid & 127, hf2 = tid >> 7;
#pragma unroll
    for (int i = 0; i < 8; ++i) {
        const int t = i * 8 + hf2 * 4;
        ushort wv[4];
#pragma unroll
        for (int jj = 0; jj < 4; ++jj) {
            int s = sv[t + jj];
            const float* sp = (s >= 0 ? v + (long)s * HD : vc + (long)(r0 + t + jj) * HD) + h * Dd + d;
            wv[jj] = f2bf(*sp);
        }
        uint2 u;
        u.x = (uint)wv[0] | ((uint)wv[1] << 16);
        u.y = (uint)wv[2] | ((uint)wv[3] << 16);
        *(uint2*)&Lt[d][t] = u;
    }
    __syncthreads();
#pragma unroll
    for (int i = 0; i < 4; ++i) {
        int c = i * 256 + tid, l = c & 31, j = (c >> 5) & 15, hf = c >> 9;
        *(uint4*)(ek + tb + (long)c * 8) = *(const uint4*)&Ks[hf * 32 + l][j * 8];
    }
#pragma unroll
    for (int i = 0; i < 4; ++i) {
        int c = i * 256 + tid, l = c & 31, ch = (c >> 5) & 7, nt = c >> 8;
        *(uint4*)(evt + tb + (long)c * 8) = *(const uint4*)&Lt[nt * 32 + l][ch * 8];
    }
}

// QK for one 64-key tile into zn0/zn1 via 4 independent MFMA chains.
#define QKB(QF) { \
    f32x16 a0 = zero16(), b0 = zero16(), a1 = zero16(), b1 = zero16(); \
    _Pragma("unroll") \
    for (int kk = 0; kk < 4; ++kk) { \
        a0 = __builtin_amdgcn_mfma_f32_32x32x16_bf16(*(const bf16x8*)&Kb[kk * 512 + koff], QF[kk], a0, 0, 0, 0); \
        a1 = __builtin_amdgcn_mfma_f32_32x32x16_bf16(*(const bf16x8*)&Kb[4096 + kk * 512 + koff], QF[kk], a1, 0, 0, 0); \
        b0 = __builtin_amdgcn_mfma_f32_32x32x16_bf16(*(const bf16x8*)&Kb[(kk + 4) * 512 + koff], QF[kk + 4], b0, 0, 0, 0); \
        b1 = __builtin_amdgcn_mfma_f32_32x32x16_bf16(*(const bf16x8*)&Kb[4096 + (kk + 4) * 512 + koff], QF[kk + 4], b1, 0, 0, 0); \
    } \
    zn0 = a0 + b0; zn1 = a1 + b1; }

// One pipeline step, as a MACRO so it is guaranteed to live in the kernel
// body (R6/R7 lesson: the same code as a lambda was NOT inlined -> all
// pipeline state went through scratch: 128 VGPR, +170 MB spill traffic).
#define STEP(S, ZC0, ZC1, MTC, ZN0, ZN1, MTN) do {                                     \
    const int kv0c = (((S) < n1) ? (S) : (S) - n1) * 64;                               \
    const int qtbc = (((S) < n1) ? jp : 7 - jp) * 256 + w * 32;                        \
    const bool liveC = (kv0c <= qtbc + 31);                                            \
    const int sp1 = (S) + 1;                                                           \
    const bool haveN = (sp1 < ns);                                                     \
    const int kv0n = haveN ? (((sp1 < n1) ? sp1 : sp1 - n1) * 64) : 0;                 \
    const int qtbn = ((sp1 < n1) ? jp : 7 - jp) * 256 + w * 32;                        \
    const bool liveN = haveN && (kv0n <= qtbn + 31);                                   \
    if ((S) + 3 < ns) stage(((S) + 3) & 3, ((S) + 3 < n1) ? (S) + 3 : (S) + 3 - n1);   \
    if (liveN) {                                                                       \
        const ushort* Kb = &KV[sp1 & 3][0];                                            \
        f32x16& zn0 = ZN0; f32x16& zn1 = ZN1;                                          \
        __builtin_amdgcn_s_setprio(1);                                                 \
        if (sp1 < n1) { QKB(qfA) } else { QKB(qfB) }                                   \
        __builtin_amdgcn_s_setprio(0);                                                 \
    }                                                                                  \
    if (liveC) {                                                                       \
        if (!__all(MTC <= m + 8.f)) {                                                  \
            const float mn_ = fmaxf(m, MTC);                                           \
            const float al = exp2f(m - mn_);                                           \
            m = mn_;                                                                   \
            lsum *= al;                                                                \
            _Pragma("unroll")                                                          \
            for (int r = 0; r < 16; ++r) {                                             \
                const float alr = __shfl(al, (r & 3) + 8 * (r >> 2) + 4 * hi);         \
                o[0][r] *= alr; o[1][r] *= alr; o[2][r] *= alr; o[3][r] *= alr;        \
            }                                                                          \
        }                                                                              \
        _Pragma("unroll")                                                              \
        for (int r = 0; r < 16; ++r) {                                                 \
            ZC0[r] = __builtin_amdgcn_exp2f(ZC0[r] - m);                               \
            ZC1[r] = __builtin_amdgcn_exp2f(ZC1[r] - m);                               \
        }                                                                              \
        lsum += hsum16(ZC0) + hsum16(ZC1);                                             \
        bf16x8 pa0 = mkfrag(cvtpk(ZC0[0], ZC0[1]), cvtpk(ZC0[2], ZC0[3]),              \
                            cvtpk(ZC0[4], ZC0[5]), cvtpk(ZC0[6], ZC0[7]), hi);         \
        bf16x8 pa1 = mkfrag(cvtpk(ZC0[8], ZC0[9]), cvtpk(ZC0[10], ZC0[11]),            \
                            cvtpk(ZC0[12], ZC0[13]), cvtpk(ZC0[14], ZC0[15]), hi);     \
        bf16x8 pa2 = mkfrag(cvtpk(ZC1[0], ZC1[1]), cvtpk(ZC1[2], ZC1[3]),              \
                            cvtpk(ZC1[4], ZC1[5]), cvtpk(ZC1[6], ZC1[7]), hi);         \
        bf16x8 pa3 = mkfrag(cvtpk(ZC1[8], ZC1[9]), cvtpk(ZC1[10], ZC1[11]),            \
                            cvtpk(ZC1[12], ZC1[13]), cvtpk(ZC1[14], ZC1[15]), hi);     \
        const ushort* Vb = &KV[(S) & 3][8192];                                         \
        __builtin_amdgcn_s_setprio(1);                                                 \
        _Pragma("unroll")                                                              \
        for (int nt = 0; nt < 4; ++nt) {                                               \
            const int vb = nt * 2048 + koff;                                           \
            o[nt] = __builtin_amdgcn_mfma_f32_32x32x16_bf16(pa0, *(const bf16x8*)&Vb[vb], o[nt], 0, 0, 0);        \
            o[nt] = __builtin_amdgcn_mfma_f32_32x32x16_bf16(pa1, *(const bf16x8*)&Vb[vb + 512], o[nt], 0, 0, 0);  \
            o[nt] = __builtin_amdgcn_mfma_f32_32x32x16_bf16(pa2, *(const bf16x8*)&Vb[vb + 1024], o[nt], 0, 0, 0); \
            o[nt] = __builtin_amdgcn_mfma_f32_32x32x16_bf16(pa3, *(const bf16x8*)&Vb[vb + 1536], o[nt], 0, 0, 0); \
        }                                                                              \
        __builtin_amdgcn_s_setprio(0);                                                 \
    }                                                                                  \
    if (liveN) {                                                                       \
        float mm = NEGINF;                                                             \
        if (kv0n + 63 > qtbn) {                                                        \
            const int qpn = qtbn + l31;                                                \
            _Pragma("unroll")                                                          \
            for (int r = 0; r < 16; ++r) {                                             \
                const int kr = kv0n + ((r & 3) + 8 * (r >> 2) + 4 * hi);               \
                float a0_ = (kr <= qpn) ? ZN0[r] : NEGINF;                             \
                float a1_ = (kr + 32 <= qpn) ? ZN1[r] : NEGINF;                        \
                ZN0[r] = a0_; ZN1[r] = a1_;                                            \
                mm = fmaxf(mm, fmaxf(a0_, a1_));                                       \
            }                                                                          \
        } else {                                                                       \
            mm = fmaxf(hmax16(ZN0), hmax16(ZN1));                                      \
        }                                                                              \
        MTN = fmaxf(mm, __shfl_xor(mm, 32));                                           \
    }                                                                                  \
    if ((S) == n1 - 1 || (S) == ns - 1) {                                              \
        const float lt = lsum + __shfl_xor(lsum, 32);                                  \
        const float inv_ = 1.f / lt;                                                   \
        _Pragma("unroll")                                                              \
        for (int r = 0; r < 16; ++r) {                                                 \
            const int qr = (r & 3) + 8 * (r >> 2) + 4 * hi;                            \
            const float ivr = __shfl(inv_, qr);                                        \
            float* op = out + ((long)(b * SEQ + qtbc + qr) * Hh + h) * Dd + l31;       \
            op[0] = o[0][r] * ivr;                                                     \
            op[32] = o[1][r] * ivr;                                                    \
            op[64] = o[2][r] * ivr;                                                    \
            op[96] = o[3][r] * ivr;                                                    \
        }                                                                              \
        _Pragma("unroll")                                                              \
        for (int nt = 0; nt < 4; ++nt) o[nt] = zero16();                               \
        m = NEGINF; lsum = 0.f;                                                        \
    }                                                                                  \
    if ((S) + 2 < ns) { asm volatile("s_waitcnt vmcnt(4)" ::: "memory"); }             \
    else              { asm volatile("s_waitcnt vmcnt(0)" ::: "memory"); }             \
    __builtin_amdgcn_sched_barrier(0);                                                 \
    __builtin_amdgcn_s_barrier();                                                      \
} while (0)

// ---- causal flash attention: software-pipelined tiles, 4-buf counted vmcnt ----
// 1 block/CU (128 KB LDS), 8 waves, full 256-VGPR budget (HK/AITER config).
__global__ __launch_bounds__(512, 1) void attn32(const float* __restrict__ q,
                                                 const ushort* __restrict__ ek,
                                                 const ushort* __restrict__ evt,
                                                 float* __restrict__ out) {
    __shared__ ushort KV[4][16384];  // 4 bufs x [K 8192 | V 8192] shorts = 128 KB

    const int tid = threadIdx.x;
    const int w = tid >> 6, lane = tid & 63;
    const int l31 = lane & 31, hi = lane >> 5;
    const int g = blockIdx.x;
    const int bh = g & 63, jp = g >> 6;
    const int b = bh >> 4, h = bh & 15;
    const int n1 = 4 * (jp + 1), ns = 36;
    const long kvbase = (long)bh * 32 * 8192;
    const int koff = hi * 256 + l31 * 8;

    bf16x8 qfA[8], qfB[8];
    auto loadq = [&](int qt_, bf16x8* qf) {
        const int qrow = qt_ * 256 + w * 32 + l31;
        const float* qp = q + ((long)(b * SEQ + qrow) * Hh + h) * Dd + hi * 8;
#pragma unroll
        for (int kk = 0; kk < 8; ++kk) {
            float4 A = *(const float4*)(qp + kk * 16);
            float4 Bv = *(const float4*)(qp + kk * 16 + 4);
            A.x *= ATT_C; A.y *= ATT_C; A.z *= ATT_C; A.w *= ATT_C;
            Bv.x *= ATT_C; Bv.y *= ATT_C; Bv.z *= ATT_C; Bv.w *= ATT_C;
            union { uint4 u; bf16x8 v; } cv;
            cv.u = pack8(A, Bv);
            qf[kk] = cv.v;
        }
    };
    auto stage = [&](int nb, int t) {
        const ushort* kg = ek + kvbase + (long)t * 8192 + tid * 8;
        const ushort* vg = evt + kvbase + (long)t * 8192 + tid * 8;
        ushort* kl = &KV[nb][tid * 8];
        ushort* vl = &KV[nb][8192 + tid * 8];
#pragma unroll
        for (int i = 0; i < 2; ++i) {
            gll16(kg + i * 4096, kl + i * 4096);
            gll16(vg + i * 4096, vl + i * 4096);
        }
    };

    f32x16 o[4];
#pragma unroll
    for (int nt = 0; nt < 4; ++nt) o[nt] = zero16();
    float m = NEGINF, lsum = 0.f;

    // ---- prologue ----
    loadq(jp, qfA);
    loadq(7 - jp, qfB);
    stage(0, 0); stage(1, 1); stage(2, 2);
    asm volatile("s_waitcnt vmcnt(8)" ::: "memory");   // tile0 loaded (per-wave)
    __builtin_amdgcn_sched_barrier(0);
    __builtin_amdgcn_s_barrier();                      // tile0 visible block-wide

    f32x16 zA0, zA1, zB0, zB1;
    float mA = NEGINF, mB = NEGINF;
    {
        const ushort* Kb = &KV[0][0];
        f32x16& zn0 = zA0; f32x16& zn1 = zA1;
        QKB(qfA);
        const int qtb0 = jp * 256 + w * 32;
        float mm = NEGINF;
        {   // masknext(kv0=0, qtb0) inline
            const int qpn = qtb0 + l31;
#pragma unroll
            for (int r = 0; r < 16; ++r) {
                const int kr = (r & 3) + 8 * (r >> 2) + 4 * hi;
                float a0_ = (kr <= qpn) ? zA0[r] : NEGINF;
                float a1_ = (kr + 32 <= qpn) ? zA1[r] : NEGINF;
                zA0[r] = a0_; zA1[r] = a1_;
                mm = fmaxf(mm, fmaxf(a0_, a1_));
            }
        }
        mA = fmaxf(mm, __shfl_xor(mm, 32));
    }
    asm volatile("s_waitcnt vmcnt(4)" ::: "memory");   // tile1 loaded
    __builtin_amdgcn_sched_barrier(0);
    __builtin_amdgcn_s_barrier();

    for (int s = 0; s < ns; s += 2) {
        STEP(s,     zA0, zA1, mA, zB0, zB1, mB);
        STEP(s + 1, zB0, zB1, mB, zA0, zA1, mA);
    }
}

extern "C" void kernel_launch(void* const* d_in, const int* in_sizes, int n_in,
                              void* d_out, int out_size, void* d_ws, size_t ws_size,
                              hipStream_t stream) {
    const float* q = (const float*)d_in[0];
    const float* k = (const float*)d_in[1];
    const float* v = (const float*)d_in[2];
    const float* k_cache = (const float*)d_in[3];
    const float* v_cache = (const float*)d_in[4];
    const int* slot_mapping = (const int*)d_in[5];
    float* out = (float*)d_out;

    const int T = in_sizes[0] / HD;  // 8192
    (void)n_in; (void)out_size; (void)ws_size;

    ushort* ek = (ushort*)d_ws;                 // fragment-major K tiles (32 MB)
    ushort* evt = ek + (size_t)T * HD;          // fragment-major V tiles (32 MB)
    int* inv = (int*)(evt + (size_t)T * HD);    // [T] inverse slot map

    initinv<<<T / 256, 256, 0, stream>>>(inv, T);
    buildinv<<<T / 256, 256, 0, stream>>>(slot_mapping, inv, T);
    fusekv<<<dim3(T / 64, Hh), 256, 0, stream>>>(k, v, k_cache, v_cache, inv, ek, evt);
    attn32<<<dim3(256), 512, 0, stream>>>(q, ek, evt, out);
}

// Round 9
// 175.242 us; speedup vs baseline: 1.3675x; 1.2790x over previous
//
#include <hip/hip_runtime.h>

typedef float f32x16 __attribute__((ext_vector_type(16)));
typedef __bf16 bf16x8 __attribute__((ext_vector_type(8)));
typedef unsigned int uint2v __attribute__((ext_vector_type(2)));

#define Hh 16
#define Dd 128
#define SEQ 2048
#define HD 2048                      // Hh*Dd
#define ATT_C 0.12751743f            // (1/sqrt(128)) * log2(e)
#define NEGINF (-__builtin_inff())

__device__ __forceinline__ ushort f2bf(float f) {
    uint u = __builtin_bit_cast(uint, f);
    return (ushort)((u + 0x7FFFu + ((u >> 16) & 1u)) >> 16);
}

__device__ __forceinline__ uint4 pack8(float4 a, float4 b) {
    uint4 u;
    u.x = (uint)f2bf(a.x) | ((uint)f2bf(a.y) << 16);
    u.y = (uint)f2bf(a.z) | ((uint)f2bf(a.w) << 16);
    u.z = (uint)f2bf(b.x) | ((uint)f2bf(b.y) << 16);
    u.w = (uint)f2bf(b.z) | ((uint)f2bf(b.w) << 16);
    return u;
}

// single-instruction packed f32->bf16 (RNE), low=a high=b
__device__ __forceinline__ uint cvtpk(float a, float b) {
    uint r;
    asm("v_cvt_pk_bf16_f32 %0, %1, %2" : "=v"(r) : "v"(a), "v"(b));
    return r;
}

__device__ __forceinline__ f32x16 zero16() {
    f32x16 v;
#pragma unroll
    for (int i = 0; i < 16; ++i) v[i] = 0.f;
    return v;
}

__device__ __forceinline__ float hmax16(const f32x16 v) {
    float a0 = fmaxf(v[0], v[1]), a1 = fmaxf(v[2], v[3]);
    float a2 = fmaxf(v[4], v[5]), a3 = fmaxf(v[6], v[7]);
    float a4 = fmaxf(v[8], v[9]), a5 = fmaxf(v[10], v[11]);
    float a6 = fmaxf(v[12], v[13]), a7 = fmaxf(v[14], v[15]);
    float b0 = fmaxf(a0, a1), b1 = fmaxf(a2, a3), b2 = fmaxf(a4, a5), b3 = fmaxf(a6, a7);
    return fmaxf(fmaxf(b0, b1), fmaxf(b2, b3));
}
__device__ __forceinline__ float hsum16(const f32x16 v) {
    float a0 = v[0] + v[1], a1 = v[2] + v[3], a2 = v[4] + v[5], a3 = v[6] + v[7];
    float a4 = v[8] + v[9], a5 = v[10] + v[11], a6 = v[12] + v[13], a7 = v[14] + v[15];
    float b0 = a0 + a1, b1 = a2 + a3, b2 = a4 + a5, b3 = a6 + a7;
    return (b0 + b1) + (b2 + b3);
}

// async global->LDS, 16 B per lane (dest must be tid-linear)
__device__ __forceinline__ void gll16(const void* g, void* l) {
    __builtin_amdgcn_global_load_lds(
        (const __attribute__((address_space(1))) unsigned int*)g,
        (__attribute__((address_space(3))) unsigned int*)l, 16, 0, 0);
}

// PV A-fragment assembly via permlane32_swap (verified R2/R4)
__device__ __forceinline__ bf16x8 mkfrag(uint a01, uint a23, uint a45, uint a67, int hi) {
    uint4 u;
#if __has_builtin(__builtin_amdgcn_permlane32_swap)
    uint2v xz = __builtin_amdgcn_permlane32_swap(a01, a45, false, false);
    uint2v yw = __builtin_amdgcn_permlane32_swap(a23, a67, false, false);
    u.x = xz[0]; u.y = yw[0]; u.z = xz[1]; u.w = yw[1];
    (void)hi;
#else
    uint s01 = __shfl_xor(a01, 32), s23 = __shfl_xor(a23, 32);
    uint s45 = __shfl_xor(a45, 32), s67 = __shfl_xor(a67, 32);
    u.x = hi ? s45 : a01;
    u.y = hi ? s67 : a23;
    u.z = hi ? a45 : s01;
    u.w = hi ? a67 : s23;
#endif
    return __builtin_bit_cast(bf16x8, u);
}

// ---- inverse slot map ----
__global__ void initinv(int* __restrict__ inv, int T) {
    int i = blockIdx.x * 256 + threadIdx.x;
    if (i < T) inv[i] = -1;
}
__global__ void buildinv(const int* __restrict__ slots, int* __restrict__ inv, int T) {
    int t = blockIdx.x * 256 + threadIdx.x;
    if (t < T) { int s = slots[t]; if (s >= 0 && s < T) inv[s] = t; }
}

// ---- fused effective-KV materialization into FRAGMENT-MAJOR 16KB tiles ----
__global__ void fusekv(const float* __restrict__ k, const float* __restrict__ v,
                       const float* __restrict__ kc, const float* __restrict__ vc,
                       const int* __restrict__ inv, ushort* __restrict__ ek,
                       ushort* __restrict__ evt) {
    __shared__ int sv[64];
    __shared__ ushort Ks[64][136];
    __shared__ ushort Lt[128][72];
    const int tid = threadIdx.x;
    const int r0 = blockIdx.x * 64, h = blockIdx.y;
    const int b = r0 >> 11, tok0 = r0 & (SEQ - 1);
    const long tb = ((long)(b * Hh + h) * 32 + (tok0 >> 6)) * 8192;
    if (tid < 64) sv[tid] = inv[r0 + tid];
    __syncthreads();
#pragma unroll
    for (int i = 0; i < 4; ++i) {
        int idx = i * 256 + tid, r = idx >> 4, sg = idx & 15;
        int s = sv[r];
        const float* src = (s >= 0 ? k + (long)s * HD : kc + (long)(r0 + r) * HD) + h * Dd + sg * 8;
        float4 A = *(const float4*)src;
        float4 Bv = *(const float4*)(src + 4);
        *(uint4*)&Ks[r][sg * 8] = pack8(A, Bv);
    }
    const int d = tid & 127, hf2 = tid >> 7;
#pragma unroll
    for (int i = 0; i < 8; ++i) {
        const int t = i * 8 + hf2 * 4;
        ushort wv[4];
#pragma unroll
        for (int jj = 0; jj < 4; ++jj) {
            int s = sv[t + jj];
            const float* sp = (s >= 0 ? v + (long)s * HD : vc + (long)(r0 + t + jj) * HD) + h * Dd + d;
            wv[jj] = f2bf(*sp);
        }
        uint2 u;
        u.x = (uint)wv[0] | ((uint)wv[1] << 16);
        u.y = (uint)wv[2] | ((uint)wv[3] << 16);
        *(uint2*)&Lt[d][t] = u;
    }
    __syncthreads();
#pragma unroll
    for (int i = 0; i < 4; ++i) {
        int c = i * 256 + tid, l = c & 31, j = (c >> 5) & 15, hf = c >> 9;
        *(uint4*)(ek + tb + (long)c * 8) = *(const uint4*)&Ks[hf * 32 + l][j * 8];
    }
#pragma unroll
    for (int i = 0; i < 4; ++i) {
        int c = i * 256 + tid, l = c & 31, ch = (c >> 5) & 7, nt = c >> 8;
        *(uint4*)(evt + tb + (long)c * 8) = *(const uint4*)&Lt[nt * 32 + l][ch * 8];
    }
}

// One 32-key half: QK (K-frag reused by u0,u1) -> per-u online softmax -> PV
// (V-frag reused by u0,u1). 32 FLOP per LDS byte (2x the QBLK=32 structure).
#define DOHALF(HH)                                                                          \
  {                                                                                         \
    const int kadd = (HH) * 4096, vadd = (HH) * 1024;                                       \
    const int kb0 = kv0 + (HH) * 32;                                                        \
    f32x16 z0 = zero16(), z1 = zero16();                                                    \
    __builtin_amdgcn_s_setprio(1);                                                          \
    _Pragma("unroll")                                                                       \
    for (int kk = 0; kk < 8; ++kk) {                                                        \
      bf16x8 kf = *(const bf16x8*)&Kb[kadd + kk * 512 + koff];                              \
      z0 = __builtin_amdgcn_mfma_f32_32x32x16_bf16(kf, qf0[kk], z0, 0, 0, 0);               \
      z1 = __builtin_amdgcn_mfma_f32_32x32x16_bf16(kf, qf1[kk], z1, 0, 0, 0);               \
    }                                                                                       \
    __builtin_amdgcn_s_setprio(0);                                                          \
    if (diag) {                                                                             \
      _Pragma("unroll")                                                                     \
      for (int r = 0; r < 16; ++r) {                                                        \
        const int kr = kb0 + ((r & 3) + 8 * (r >> 2) + 4 * hi);                             \
        z0[r] = (kr <= qp0) ? z0[r] : NEGINF;                                               \
        z1[r] = (kr <= qp1) ? z1[r] : NEGINF;                                               \
      }                                                                                     \
    }                                                                                       \
    float mt0 = hmax16(z0), mt1 = hmax16(z1);                                               \
    mt0 = fmaxf(mt0, __shfl_xor(mt0, 32));                                                  \
    mt1 = fmaxf(mt1, __shfl_xor(mt1, 32));                                                  \
    if (!(__all(mt0 <= ms0 + 8.f) && __all(mt1 <= ms1 + 8.f))) {                            \
      const float mn0 = fmaxf(ms0, mt0), mn1 = fmaxf(ms1, mt1);                             \
      const float al0 = exp2f(ms0 - mn0), al1 = exp2f(ms1 - mn1);                           \
      ms0 = mn0; ms1 = mn1; ls0 *= al0; ls1 *= al1;                                         \
      _Pragma("unroll")                                                                     \
      for (int r = 0; r < 16; ++r) {                                                        \
        const int pr = (r & 3) + 8 * (r >> 2) + 4 * hi;                                     \
        const float a0_ = __shfl(al0, pr), a1_ = __shfl(al1, pr);                           \
        o[0][r] *= a0_; o[1][r] *= a0_; o[2][r] *= a0_; o[3][r] *= a0_;                     \
        o[4][r] *= a1_; o[5][r] *= a1_; o[6][r] *= a1_; o[7][r] *= a1_;                     \
      }                                                                                     \
    }                                                                                       \
    _Pragma("unroll")                                                                       \
    for (int r = 0; r < 16; ++r) {                                                          \
      z0[r] = __builtin_amdgcn_exp2f(z0[r] - ms0);                                          \
      z1[r] = __builtin_amdgcn_exp2f(z1[r] - ms1);                                          \
    }                                                                                       \
    ls0 += hsum16(z0); ls1 += hsum16(z1);                                                   \
    bf16x8 pa00 = mkfrag(cvtpk(z0[0], z0[1]), cvtpk(z0[2], z0[3]),                          \
                         cvtpk(z0[4], z0[5]), cvtpk(z0[6], z0[7]), hi);                     \
    bf16x8 pa01 = mkfrag(cvtpk(z0[8], z0[9]), cvtpk(z0[10], z0[11]),                        \
                         cvtpk(z0[12], z0[13]), cvtpk(z0[14], z0[15]), hi);                 \
    bf16x8 pa10 = mkfrag(cvtpk(z1[0], z1[1]), cvtpk(z1[2], z1[3]),                          \
                         cvtpk(z1[4], z1[5]), cvtpk(z1[6], z1[7]), hi);                     \
    bf16x8 pa11 = mkfrag(cvtpk(z1[8], z1[9]), cvtpk(z1[10], z1[11]),                        \
                         cvtpk(z1[12], z1[13]), cvtpk(z1[14], z1[15]), hi);                 \
    __builtin_amdgcn_s_setprio(1);                                                          \
    _Pragma("unroll")                                                                       \
    for (int nt = 0; nt < 4; ++nt) {                                                        \
      const int vb = nt * 2048 + koff + vadd;                                               \
      bf16x8 vf0 = *(const bf16x8*)&Vb[vb];                                                 \
      bf16x8 vf1 = *(const bf16x8*)&Vb[vb + 512];                                           \
      o[nt]     = __builtin_amdgcn_mfma_f32_32x32x16_bf16(pa00, vf0, o[nt], 0, 0, 0);       \
      o[nt]     = __builtin_amdgcn_mfma_f32_32x32x16_bf16(pa01, vf1, o[nt], 0, 0, 0);       \
      o[4 + nt] = __builtin_amdgcn_mfma_f32_32x32x16_bf16(pa10, vf0, o[4 + nt], 0, 0, 0);   \
      o[4 + nt] = __builtin_amdgcn_mfma_f32_32x32x16_bf16(pa11, vf1, o[4 + nt], 0, 0, 0);   \
    }                                                                                       \
    __builtin_amdgcn_s_setprio(0);                                                          \
  }

// ---- causal flash attention: 4 waves x 64 q-rows (K/V-frag 2x register reuse),
// 2 LDS buffers (64 KB), 2 blocks/CU, explicit waves_per_eu(2) -> 256-VGPR budget.
__global__ __launch_bounds__(256) __attribute__((amdgpu_waves_per_eu(2)))
void attn32(const float* __restrict__ q, const ushort* __restrict__ ek,
            const ushort* __restrict__ evt, float* __restrict__ out) {
    __shared__ ushort KV[2][16384];  // [buf][ K tile 8192 | V tile 8192 ] shorts

    const int tid = threadIdx.x;
    const int w = tid >> 6, lane = tid & 63;
    const int l31 = lane & 31, hi = lane >> 5;
    const int g = blockIdx.x;
    const int bh = g & 63, ig = g >> 6;
    const int jj = (ig < 4) ? ig : 11 - ig;   // blocks g and g+256 complementary (36 steps/pair)
    const int b = bh >> 4, h = bh & 15;
    const int ns = 4 * (jj + 1);
    const long kvbase = (long)bh * 32 * 8192;
    const int koff = hi * 256 + l31 * 8;
    const int qtb = jj * 256 + w * 64;        // wave owns 64 q-rows
    const int qp0 = qtb + l31, qp1 = qtb + 32 + l31;

    bf16x8 qf0[8], qf1[8];
    auto loadq = [&](int qrow, bf16x8* qf) {
        const float* qp = q + ((long)(b * SEQ + qrow) * Hh + h) * Dd + hi * 8;
#pragma unroll
        for (int kk = 0; kk < 8; ++kk) {
            float4 A = *(const float4*)(qp + kk * 16);
            float4 Bv = *(const float4*)(qp + kk * 16 + 4);
            A.x *= ATT_C; A.y *= ATT_C; A.z *= ATT_C; A.w *= ATT_C;
            Bv.x *= ATT_C; Bv.y *= ATT_C; Bv.z *= ATT_C; Bv.w *= ATT_C;
            union { uint4 u; bf16x8 v; } cv;
            cv.u = pack8(A, Bv);
            qf[kk] = cv.v;
        }
    };
    auto stage = [&](int nb, int t) {
        const ushort* kg = ek + kvbase + (long)t * 8192 + tid * 8;
        const ushort* vg = evt + kvbase + (long)t * 8192 + tid * 8;
        ushort* kl = &KV[nb][tid * 8];
        ushort* vl = &KV[nb][8192 + tid * 8];
#pragma unroll
        for (int i = 0; i < 4; ++i) {
            gll16(kg + i * 2048, kl + i * 2048);
            gll16(vg + i * 2048, vl + i * 2048);
        }
    };

    loadq(qtb + l31, qf0);
    loadq(qtb + 32 + l31, qf1);

    f32x16 o[8];
#pragma unroll
    for (int nt = 0; nt < 8; ++nt) o[nt] = zero16();
    float ms0 = NEGINF, ms1 = NEGINF, ls0 = 0.f, ls1 = 0.f;

    stage(0, 0);
    __syncthreads();

    int cur = 0;
    for (int s = 0; s < ns; ++s) {
        if (s + 1 < ns) stage(cur ^ 1, s + 1);
        const int kv0 = s * 64;
        if (kv0 <= qtb + 63) {                        // wave has live keys this step
            const ushort* Kb = &KV[cur][0];
            const ushort* Vb = &KV[cur][8192];
            const bool diag = (kv0 + 63 > qtb);       // any masking needed
            const bool h2 = (kv0 + 32 <= qtb + 63);   // second 32-key half live
            DOHALF(0);
            if (h2) DOHALF(1);
        }
        __syncthreads();  // drains this step's stage (issued ~full step ago) + publishes buffer
        cur ^= 1;
    }

    // ---- epilogue: both q-blocks ----
    const float lt0 = ls0 + __shfl_xor(ls0, 32);
    const float lt1 = ls1 + __shfl_xor(ls1, 32);
    const float iv0 = 1.f / lt0, iv1 = 1.f / lt1;
#pragma unroll
    for (int r = 0; r < 16; ++r) {
        const int qr = (r & 3) + 8 * (r >> 2) + 4 * hi;
        const float a0 = __shfl(iv0, qr), a1 = __shfl(iv1, qr);
        float* op0 = out + ((long)(b * SEQ + qtb + qr) * Hh + h) * Dd + l31;
        float* op1 = out + ((long)(b * SEQ + qtb + 32 + qr) * Hh + h) * Dd + l31;
        op0[0]  = o[0][r] * a0;
        op0[32] = o[1][r] * a0;
        op0[64] = o[2][r] * a0;
        op0[96] = o[3][r] * a0;
        op1[0]  = o[4][r] * a1;
        op1[32] = o[5][r] * a1;
        op1[64] = o[6][r] * a1;
        op1[96] = o[7][r] * a1;
    }
}

extern "C" void kernel_launch(void* const* d_in, const int* in_sizes, int n_in,
                              void* d_out, int out_size, void* d_ws, size_t ws_size,
                              hipStream_t stream) {
    const float* q = (const float*)d_in[0];
    const float* k = (const float*)d_in[1];
    const float* v = (const float*)d_in[2];
    const float* k_cache = (const float*)d_in[3];
    const float* v_cache = (const float*)d_in[4];
    const int* slot_mapping = (const int*)d_in[5];
    float* out = (float*)d_out;

    const int T = in_sizes[0] / HD;  // 8192
    (void)n_in; (void)out_size; (void)ws_size;

    ushort* ek = (ushort*)d_ws;                 // fragment-major K tiles (32 MB)
    ushort* evt = ek + (size_t)T * HD;          // fragment-major V tiles (32 MB)
    int* inv = (int*)(evt + (size_t)T * HD);    // [T] inverse slot map

    initinv<<<T / 256, 256, 0, stream>>>(inv, T);
    buildinv<<<T / 256, 256, 0, stream>>>(slot_mapping, inv, T);
    fusekv<<<dim3(T / 64, Hh), 256, 0, stream>>>(k, v, k_cache, v_cache, inv, ek, evt);
    attn32<<<dim3(512), 256, 0, stream>>>(q, ek, evt, out);
}

// Round 10
// 153.476 us; speedup vs baseline: 1.5615x; 1.1418x over previous
//
#include <hip/hip_runtime.h>

typedef float f32x16 __attribute__((ext_vector_type(16)));
typedef __bf16 bf16x8 __attribute__((ext_vector_type(8)));
typedef unsigned int uint2v __attribute__((ext_vector_type(2)));

#define Hh 16
#define Dd 128
#define SEQ 2048
#define HD 2048                      // Hh*Dd
#define ATT_C 0.12751743f            // (1/sqrt(128)) * log2(e)
#define NEGINF (-__builtin_inff())

__device__ __forceinline__ ushort f2bf(float f) {
    uint u = __builtin_bit_cast(uint, f);
    return (ushort)((u + 0x7FFFu + ((u >> 16) & 1u)) >> 16);
}

__device__ __forceinline__ uint4 pack8(float4 a, float4 b) {
    uint4 u;
    u.x = (uint)f2bf(a.x) | ((uint)f2bf(a.y) << 16);
    u.y = (uint)f2bf(a.z) | ((uint)f2bf(a.w) << 16);
    u.z = (uint)f2bf(b.x) | ((uint)f2bf(b.y) << 16);
    u.w = (uint)f2bf(b.z) | ((uint)f2bf(b.w) << 16);
    return u;
}

// single-instruction packed f32->bf16 (RNE), low=a high=b
__device__ __forceinline__ uint cvtpk(float a, float b) {
    uint r;
    asm("v_cvt_pk_bf16_f32 %0, %1, %2" : "=v"(r) : "v"(a), "v"(b));
    return r;
}

__device__ __forceinline__ f32x16 zero16() {
    f32x16 v;
#pragma unroll
    for (int i = 0; i < 16; ++i) v[i] = 0.f;
    return v;
}

// async global->LDS, 16 B per lane (dest must be tid-linear)
__device__ __forceinline__ void gll16(const void* g, void* l) {
    __builtin_amdgcn_global_load_lds(
        (const __attribute__((address_space(1))) unsigned int*)g,
        (__attribute__((address_space(3))) unsigned int*)l, 16, 0, 0);
}

// PV A-fragment assembly via permlane32_swap (verified R2/R4)
__device__ __forceinline__ bf16x8 mkfrag(uint a01, uint a23, uint a45, uint a67, int hi) {
    uint4 u;
#if __has_builtin(__builtin_amdgcn_permlane32_swap)
    uint2v xz = __builtin_amdgcn_permlane32_swap(a01, a45, false, false);
    uint2v yw = __builtin_amdgcn_permlane32_swap(a23, a67, false, false);
    u.x = xz[0]; u.y = yw[0]; u.z = xz[1]; u.w = yw[1];
    (void)hi;
#else
    uint s01 = __shfl_xor(a01, 32), s23 = __shfl_xor(a23, 32);
    uint s45 = __shfl_xor(a45, 32), s67 = __shfl_xor(a67, 32);
    u.x = hi ? s45 : a01;
    u.y = hi ? s67 : a23;
    u.z = hi ? a45 : s01;
    u.w = hi ? a67 : s23;
#endif
    return __builtin_bit_cast(bf16x8, u);
}

// ---- inverse slot map ----
__global__ void initinv(int* __restrict__ inv, int T) {
    int i = blockIdx.x * 256 + threadIdx.x;
    if (i < T) inv[i] = -1;
}
__global__ void buildinv(const int* __restrict__ slots, int* __restrict__ inv, int T) {
    int t = blockIdx.x * 256 + threadIdx.x;
    if (t < T) { int s = slots[t]; if (s >= 0 && s < T) inv[s] = t; }
}

// ---- fused effective-KV materialization into FRAGMENT-MAJOR 16KB tiles ----
__global__ void fusekv(const float* __restrict__ k, const float* __restrict__ v,
                       const float* __restrict__ kc, const float* __restrict__ vc,
                       const int* __restrict__ inv, ushort* __restrict__ ek,
                       ushort* __restrict__ evt) {
    __shared__ int sv[64];
    __shared__ ushort Ks[64][136];
    __shared__ ushort Lt[128][72];
    const int tid = threadIdx.x;
    const int r0 = blockIdx.x * 64, h = blockIdx.y;
    const int b = r0 >> 11, tok0 = r0 & (SEQ - 1);
    const long tb = ((long)(b * Hh + h) * 32 + (tok0 >> 6)) * 8192;
    if (tid < 64) sv[tid] = inv[r0 + tid];
    __syncthreads();
#pragma unroll
    for (int i = 0; i < 4; ++i) {
        int idx = i * 256 + tid, r = idx >> 4, sg = idx & 15;
        int s = sv[r];
        const float* src = (s >= 0 ? k + (long)s * HD : kc + (long)(r0 + r) * HD) + h * Dd + sg * 8;
        float4 A = *(const float4*)src;
        float4 Bv = *(const float4*)(src + 4);
        *(uint4*)&Ks[r][sg * 8] = pack8(A, Bv);
    }
    const int d = tid & 127, hf2 = tid >> 7;
#pragma unroll
    for (int i = 0; i < 8; ++i) {
        const int t = i * 8 + hf2 * 4;
        ushort wv[4];
#pragma unroll
        for (int jj = 0; jj < 4; ++jj) {
            int s = sv[t + jj];
            const float* sp = (s >= 0 ? v + (long)s * HD : vc + (long)(r0 + t + jj) * HD) + h * Dd + d;
            wv[jj] = f2bf(*sp);
        }
        uint2 u;
        u.x = (uint)wv[0] | ((uint)wv[1] << 16);
        u.y = (uint)wv[2] | ((uint)wv[3] << 16);
        *(uint2*)&Lt[d][t] = u;
    }
    __syncthreads();
#pragma unroll
    for (int i = 0; i < 4; ++i) {
        int c = i * 256 + tid, l = c & 31, j = (c >> 5) & 15, hf = c >> 9;
        *(uint4*)(ek + tb + (long)c * 8) = *(const uint4*)&Ks[hf * 32 + l][j * 8];
    }
#pragma unroll
    for (int i = 0; i < 4; ++i) {
        int c = i * 256 + tid, l = c & 31, ch = (c >> 5) & 7, nt = c >> 8;
        *(uint4*)(evt + tb + (long)c * 8) = *(const uint4*)&Lt[nt * 32 + l][ch * 8];
    }
}

// ---- causal flash attention: 8 waves / 256-row qtile, 3-buf counted-vmcnt ----
// R5 compute structure unchanged; only the memory pipeline differs:
// 3 LDS buffers, stage issued 2 steps ahead, vmcnt(8)+s_barrier (never drain to 0).
__global__ __launch_bounds__(512, 2) void attn32(const float* __restrict__ q,
                                                 const ushort* __restrict__ ek,
                                                 const ushort* __restrict__ evt,
                                                 float* __restrict__ out) {
    __shared__ ushort KV[3][16384];  // [buf][ K tile 8192 | V tile 8192 ] shorts = 96 KB

    const int tid = threadIdx.x;
    const int w = tid >> 6, lane = tid & 63;
    const int l31 = lane & 31, hi = lane >> 5;
    const int g = blockIdx.x;
    const int bh = g & 63, jp = g >> 6;   // all 4 pair-blocks of a bh on XCD bh%8
    const int b = bh >> 4, h = bh & 15;
    const int n1 = 4 * (jp + 1), ns = 36; // phase1: qtile jp, phase2: qtile 7-jp
    const long kvbase = (long)bh * 32 * 8192;
    const int koff = hi * 256 + l31 * 8;

    bf16x8 qf[8];
    auto loadq = [&](int qt_) {
        const int qrow = qt_ * 256 + w * 32 + l31;
        const float* qp = q + ((long)(b * SEQ + qrow) * Hh + h) * Dd + hi * 8;
#pragma unroll
        for (int kk = 0; kk < 8; ++kk) {
            float4 A = *(const float4*)(qp + kk * 16);
            float4 Bv = *(const float4*)(qp + kk * 16 + 4);
            A.x *= ATT_C; A.y *= ATT_C; A.z *= ATT_C; A.w *= ATT_C;
            Bv.x *= ATT_C; Bv.y *= ATT_C; Bv.z *= ATT_C; Bv.w *= ATT_C;
            union { uint4 u; bf16x8 v; } cv;
            cv.u = pack8(A, Bv);
            qf[kk] = cv.v;
        }
    };
    auto stage = [&](int nb, int t) {
        const ushort* kg = ek + kvbase + (long)t * 8192 + tid * 8;
        const ushort* vg = evt + kvbase + (long)t * 8192 + tid * 8;
        ushort* kl = &KV[nb][tid * 8];
        ushort* vl = &KV[nb][8192 + tid * 8];
#pragma unroll
        for (int i = 0; i < 2; ++i) {
            gll16(kg + i * 4096, kl + i * 4096);
            gll16(vg + i * 4096, vl + i * 4096);
        }
    };

    f32x16 o[4];
#pragma unroll
    for (int nt = 0; nt < 4; ++nt) o[nt] = zero16();
    float m = NEGINF, lsum = 0.f;

    // ---- prologue: Q for phase 1; prefetch tiles 0 and 1 ----
    loadq(jp);
    stage(0, 0);
    stage(1, 1);
    asm volatile("s_waitcnt vmcnt(8)" ::: "memory");  // Q + tile0 done; tile1 in flight
    __builtin_amdgcn_sched_barrier(0);
    __builtin_amdgcn_s_barrier();

    int qt = jp, qtb = qt * 256 + w * 32;

    for (int s = 0; s < ns; ++s) {
        // stage 2 tiles ahead into buffer (s+2)%3
        if (s + 2 < ns) {
            const int t2 = (s + 2 < n1) ? s + 2 : s + 2 - n1;
            stage((s + 2) % 3, t2);
        }
        if (s == n1) { qt = 7 - jp; qtb = qt * 256 + w * 32; loadq(qt); }
        const int kv0 = ((s < n1) ? s : s - n1) * 64;
        const int qpos = qtb + l31;
        const ushort* Kb = &KV[s % 3][0];
        const ushort* Vb = &KV[s % 3][8192];

        if (kv0 <= qtb + 31) {
            const bool h2full = (kv0 + 32 <= qtb + 31);
            f32x16 s0 = zero16(), s1;
            __builtin_amdgcn_s_setprio(1);
            if (h2full) {
                s1 = zero16();
#pragma unroll
                for (int kk = 0; kk < 8; ++kk) {  // two independent chains
                    s0 = __builtin_amdgcn_mfma_f32_32x32x16_bf16(
                        *(const bf16x8*)&Kb[kk * 512 + koff], qf[kk], s0, 0, 0, 0);
                    s1 = __builtin_amdgcn_mfma_f32_32x32x16_bf16(
                        *(const bf16x8*)&Kb[4096 + kk * 512 + koff], qf[kk], s1, 0, 0, 0);
                }
            } else {
#pragma unroll
                for (int kk = 0; kk < 8; ++kk)
                    s0 = __builtin_amdgcn_mfma_f32_32x32x16_bf16(
                        *(const bf16x8*)&Kb[kk * 512 + koff], qf[kk], s0, 0, 0, 0);
            }
            __builtin_amdgcn_s_setprio(0);

            // ---- causal mask + tile max (scale pre-folded into Q) ----
            float mt = NEGINF;
            const bool needmask = (kv0 + 63 > qtb);
            if (needmask) {
#pragma unroll
                for (int r = 0; r < 16; ++r) {
                    const int kr = kv0 + ((r & 3) + 8 * (r >> 2) + 4 * hi);
                    float a0 = (kr <= qpos) ? s0[r] : NEGINF;
                    s0[r] = a0;
                    mt = fmaxf(mt, a0);
                }
                if (h2full) {
#pragma unroll
                    for (int r = 0; r < 16; ++r) {
                        const int kr = kv0 + 32 + ((r & 3) + 8 * (r >> 2) + 4 * hi);
                        float a1 = (kr <= qpos) ? s1[r] : NEGINF;
                        s1[r] = a1;
                        mt = fmaxf(mt, a1);
                    }
                }
            } else {
#pragma unroll
                for (int r = 0; r < 16; ++r) mt = fmaxf(mt, fmaxf(s0[r], s1[r]));
            }
            mt = fmaxf(mt, __shfl_xor(mt, 32));

            // ---- defer-max rescale (THR=8 in log2 domain) ----
            if (!__all(mt <= m + 8.f)) {
                const float mn = fmaxf(m, mt);
                const float al = exp2f(m - mn);
                m = mn;
                lsum *= al;
#pragma unroll
                for (int r = 0; r < 16; ++r) {
                    const float alr = __shfl(al, (r & 3) + 8 * (r >> 2) + 4 * hi);
                    o[0][r] *= alr; o[1][r] *= alr; o[2][r] *= alr; o[3][r] *= alr;
                }
            }

            // ---- P = exp2(z - m), row sum ----
            float psum = 0.f;
#pragma unroll
            for (int r = 0; r < 16; ++r) {
                s0[r] = __builtin_amdgcn_exp2f(s0[r] - m);
                psum += s0[r];
            }
            if (h2full) {
#pragma unroll
                for (int r = 0; r < 16; ++r) {
                    s1[r] = __builtin_amdgcn_exp2f(s1[r] - m);
                    psum += s1[r];
                }
            }
            lsum += psum;

            // ---- pack P -> A-fragments (v_cvt_pk_bf16_f32 + permlane) ----
            bf16x8 pa00 = mkfrag(cvtpk(s0[0], s0[1]), cvtpk(s0[2], s0[3]),
                                 cvtpk(s0[4], s0[5]), cvtpk(s0[6], s0[7]), hi);
            bf16x8 pa01 = mkfrag(cvtpk(s0[8], s0[9]), cvtpk(s0[10], s0[11]),
                                 cvtpk(s0[12], s0[13]), cvtpk(s0[14], s0[15]), hi);
            __builtin_amdgcn_s_setprio(1);
#pragma unroll
            for (int nt = 0; nt < 4; ++nt) {
                const int vb = nt * 2048 + koff;
                o[nt] = __builtin_amdgcn_mfma_f32_32x32x16_bf16(
                    pa00, *(const bf16x8*)&Vb[vb], o[nt], 0, 0, 0);
                o[nt] = __builtin_amdgcn_mfma_f32_32x32x16_bf16(
                    pa01, *(const bf16x8*)&Vb[vb + 512], o[nt], 0, 0, 0);
            }
            __builtin_amdgcn_s_setprio(0);
            if (h2full) {
                bf16x8 pa10 = mkfrag(cvtpk(s1[0], s1[1]), cvtpk(s1[2], s1[3]),
                                     cvtpk(s1[4], s1[5]), cvtpk(s1[6], s1[7]), hi);
                bf16x8 pa11 = mkfrag(cvtpk(s1[8], s1[9]), cvtpk(s1[10], s1[11]),
                                     cvtpk(s1[12], s1[13]), cvtpk(s1[14], s1[15]), hi);
                __builtin_amdgcn_s_setprio(1);
#pragma unroll
                for (int nt = 0; nt < 4; ++nt) {
                    const int vb = nt * 2048 + koff;
                    o[nt] = __builtin_amdgcn_mfma_f32_32x32x16_bf16(
                        pa10, *(const bf16x8*)&Vb[vb + 1024], o[nt], 0, 0, 0);
                    o[nt] = __builtin_amdgcn_mfma_f32_32x32x16_bf16(
                        pa11, *(const bf16x8*)&Vb[vb + 1536], o[nt], 0, 0, 0);
                }
                __builtin_amdgcn_s_setprio(0);
            }
        }

        if (s == n1 - 1 || s == ns - 1) {
            const float lt = lsum + __shfl_xor(lsum, 32);
            const float inv_ = 1.f / lt;
#pragma unroll
            for (int r = 0; r < 16; ++r) {
                const int qr = (r & 3) + 8 * (r >> 2) + 4 * hi;
                const float ivr = __shfl(inv_, qr);
                float* op = out + ((long)(b * SEQ + qtb + qr) * Hh + h) * Dd + l31;
                op[0]  = o[0][r] * ivr;
                op[32] = o[1][r] * ivr;
                op[64] = o[2][r] * ivr;
                op[96] = o[3][r] * ivr;
            }
#pragma unroll
            for (int nt = 0; nt < 4; ++nt) o[nt] = zero16();
            m = NEGINF; lsum = 0.f;
        }

        // counted wait: only the newest stage (8 loads) may stay in flight;
        // guarantees buffer (s+1)%3 is fully written before the next step.
        if (s + 2 < ns) { asm volatile("s_waitcnt vmcnt(8)" ::: "memory"); }
        else            { asm volatile("s_waitcnt vmcnt(0)" ::: "memory"); }
        __builtin_amdgcn_sched_barrier(0);
        __builtin_amdgcn_s_barrier();
    }
}

extern "C" void kernel_launch(void* const* d_in, const int* in_sizes, int n_in,
                              void* d_out, int out_size, void* d_ws, size_t ws_size,
                              hipStream_t stream) {
    const float* q = (const float*)d_in[0];
    const float* k = (const float*)d_in[1];
    const float* v = (const float*)d_in[2];
    const float* k_cache = (const float*)d_in[3];
    const float* v_cache = (const float*)d_in[4];
    const int* slot_mapping = (const int*)d_in[5];
    float* out = (float*)d_out;

    const int T = in_sizes[0] / HD;  // 8192
    (void)n_in; (void)out_size; (void)ws_size;

    ushort* ek = (ushort*)d_ws;                 // fragment-major K tiles (32 MB)
    ushort* evt = ek + (size_t)T * HD;          // fragment-major V tiles (32 MB)
    int* inv = (int*)(evt + (size_t)T * HD);    // [T] inverse slot map

    initinv<<<T / 256, 256, 0, stream>>>(inv, T);
    buildinv<<<T / 256, 256, 0, stream>>>(slot_mapping, inv, T);
    fusekv<<<dim3(T / 64, Hh), 256, 0, stream>>>(k, v, k_cache, v_cache, inv, ek, evt);
    attn32<<<dim3(256), 512, 0, stream>>>(q, ek, evt, out);
}